// Round 1
// baseline (181.884 us; speedup 1.0000x reference)
//
#include <hip/hip_runtime.h>

// DeepFM fused forward: gather + FM(2nd order) + dense(1st order) + 3-layer MLP.
// B=2048, one block handles RPB=8 rows; grid = 256 blocks x 256 threads.
// All fp32 (no fp32 MFMA on CDNA4; total MLP work is only ~250 MFLOP).

#define RPB 8
#define BATCH 2048
#define NF 151193  // sum(VOCABS)+1

// field offsets into the one-hot feature space (cumsum of VOCABS)
#define OFF0 0
#define OFF1 100000
#define OFF2 150000
#define OFF3 150010
#define OFF4 150013
#define OFF5 150113
#define OFF6 150163
#define OFF7 151163
#define OFF8 151187

__global__ __launch_bounds__(256, 1) void deepfm_fused(
    const int* __restrict__ f_user, const int* __restrict__ f_item,
    const int* __restrict__ f_age, const int* __restrict__ f_gender,
    const int* __restrict__ f_city, const int* __restrict__ f_cat,
    const int* __restrict__ f_brand, const int* __restrict__ f_hour,
    const int* __restrict__ f_dev, const float* __restrict__ price,
    const float* __restrict__ e_user, const float* __restrict__ e_item,
    const float* __restrict__ e_age, const float* __restrict__ e_gender,
    const float* __restrict__ e_city, const float* __restrict__ e_cat,
    const float* __restrict__ e_brand, const float* __restrict__ e_hour,
    const float* __restrict__ e_dev,
    const float* __restrict__ w_dense, const float* __restrict__ b_dense,
    const float* __restrict__ fm_v,
    const float* __restrict__ W1, const float* __restrict__ b1,
    const float* __restrict__ W2, const float* __restrict__ b2,
    const float* __restrict__ W3, const float* __restrict__ b3,
    const float* __restrict__ Wo, const float* __restrict__ bo,
    float* __restrict__ out)
{
    __shared__ float x[RPB][80];       // deep_in (77, padded)
    __shared__ float h1s[RPB][256];
    __shared__ float h2s[RPB][128];
    __shared__ float h3s[RPB][64];
    __shared__ float p2[RPB][128];     // layer2 partial (half 1)
    __shared__ float p3[3][RPB][64];   // layer3 partials (quarters 1..3)
    __shared__ float row_extra[RPB];   // dense + FM logit per row
    __shared__ float spx[RPB];         // raw price per row
    __shared__ int   sid[RPB][9];

    const int tid  = threadIdx.x;
    const int base = blockIdx.x * RPB;

    // ---- Phase A: load ids + price (8 threads, 10 loads each, independent)
    if (tid < RPB) {
        const int gr = base + tid;
        sid[tid][0] = f_user[gr];
        sid[tid][1] = f_item[gr];
        sid[tid][2] = f_age[gr];
        sid[tid][3] = f_gender[gr];
        sid[tid][4] = f_city[gr];
        sid[tid][5] = f_cat[gr];
        sid[tid][6] = f_brand[gr];
        sid[tid][7] = f_hour[gr];
        sid[tid][8] = f_dev[gr];
        spx[tid]    = price[gr];
    }
    __syncthreads();

    // ---- Phase B1: embedding gather (32 lanes per row)
    {
        const int r = tid >> 5, l = tid & 31;
        if (l < 16) x[r][ 0 + l] = e_user  [sid[r][0] * 16 + l];
        if (l < 16) x[r][16 + l] = e_item  [sid[r][1] * 16 + l];
        if (l <  8) x[r][32 + l] = e_age   [sid[r][2] *  8 + l];
        if (l <  4) x[r][40 + l] = e_gender[sid[r][3] *  4 + l];
        if (l <  8) x[r][44 + l] = e_city  [sid[r][4] *  8 + l];
        if (l <  8) x[r][52 + l] = e_cat   [sid[r][5] *  8 + l];
        if (l <  8) x[r][60 + l] = e_brand [sid[r][6] *  8 + l];
        if (l <  4) x[r][68 + l] = e_hour  [sid[r][7] *  4 + l];
        if (l <  4) x[r][72 + l] = e_dev   [sid[r][8] *  4 + l];
        if (l == 0) x[r][76]     = spx[r];            // raw price in deep_in
    }

    // ---- Phase B2: FM 2nd-order + 1st-order dense (16 lanes per row)
    if (tid < RPB * 16) {
        const int r = tid >> 4, k = tid & 15;
        const float px = spx[r] * (1.0f / 1000.0f);   // scaled price feature
        float v, s, ssq;
        v = fm_v[(NF - 1) * 16 + k];
        s = px * v; ssq = s * s;                      // (px*v)^2
        v = fm_v[(OFF0 + sid[r][0]) * 16 + k]; s += v; ssq += v * v;
        v = fm_v[(OFF1 + sid[r][1]) * 16 + k]; s += v; ssq += v * v;
        v = fm_v[(OFF2 + sid[r][2]) * 16 + k]; s += v; ssq += v * v;
        v = fm_v[(OFF3 + sid[r][3]) * 16 + k]; s += v; ssq += v * v;
        v = fm_v[(OFF4 + sid[r][4]) * 16 + k]; s += v; ssq += v * v;
        v = fm_v[(OFF5 + sid[r][5]) * 16 + k]; s += v; ssq += v * v;
        v = fm_v[(OFF6 + sid[r][6]) * 16 + k]; s += v; ssq += v * v;
        v = fm_v[(OFF7 + sid[r][7]) * 16 + k]; s += v; ssq += v * v;
        v = fm_v[(OFF8 + sid[r][8]) * 16 + k]; s += v; ssq += v * v;
        float q = 0.5f * (s * s - ssq);
        if (k == 0) {  // 1st-order dense part on lane 0 (10 independent loads)
            float d = b_dense[0] + px * w_dense[NF - 1];
            d += w_dense[OFF0 + sid[r][0]];
            d += w_dense[OFF1 + sid[r][1]];
            d += w_dense[OFF2 + sid[r][2]];
            d += w_dense[OFF3 + sid[r][3]];
            d += w_dense[OFF4 + sid[r][4]];
            d += w_dense[OFF5 + sid[r][5]];
            d += w_dense[OFF6 + sid[r][6]];
            d += w_dense[OFF7 + sid[r][7]];
            d += w_dense[OFF8 + sid[r][8]];
            q += d;
        }
        q += __shfl_xor(q, 8);
        q += __shfl_xor(q, 4);
        q += __shfl_xor(q, 2);
        q += __shfl_xor(q, 1);
        if (k == 0) row_extra[r] = q;
    }
    __syncthreads();

    // ---- Layer 1: (8 x 77) @ (77 x 256) ; thread j = tid computes col j for all rows
    {
        float acc[RPB];
        #pragma unroll
        for (int r = 0; r < RPB; ++r) acc[r] = 0.0f;
        #pragma unroll 11
        for (int i = 0; i < 77; ++i) {
            const float w = W1[i * 256 + tid];
            #pragma unroll
            for (int r = 0; r < RPB; ++r) acc[r] = fmaf(x[r][i], w, acc[r]);
        }
        const float bb = b1[tid];
        #pragma unroll
        for (int r = 0; r < RPB; ++r) h1s[r][tid] = fmaxf(acc[r] + bb, 0.0f);
    }
    __syncthreads();

    // ---- Layer 2: (8 x 256) @ (256 x 128), split-K by 2
    {
        const int j = tid & 127, half = tid >> 7;
        const float* W2p = W2 + half * 128 * 128;
        float acc[RPB];
        #pragma unroll
        for (int r = 0; r < RPB; ++r) acc[r] = 0.0f;
        #pragma unroll 16
        for (int i = 0; i < 128; ++i) {
            const float w = W2p[i * 128 + j];
            #pragma unroll
            for (int r = 0; r < RPB; ++r) acc[r] = fmaf(h1s[r][half * 128 + i], w, acc[r]);
        }
        if (half == 1) {
            #pragma unroll
            for (int r = 0; r < RPB; ++r) p2[r][j] = acc[r];
        }
        __syncthreads();
        if (half == 0) {
            const float bb = b2[j];
            #pragma unroll
            for (int r = 0; r < RPB; ++r)
                h2s[r][j] = fmaxf(acc[r] + p2[r][j] + bb, 0.0f);
        }
    }
    __syncthreads();

    // ---- Layer 3: (8 x 128) @ (128 x 64), split-K by 4
    {
        const int j = tid & 63, q4 = tid >> 6;
        const float* W3p = W3 + q4 * 32 * 64;
        float acc[RPB];
        #pragma unroll
        for (int r = 0; r < RPB; ++r) acc[r] = 0.0f;
        #pragma unroll 16
        for (int i = 0; i < 32; ++i) {
            const float w = W3p[i * 64 + j];
            #pragma unroll
            for (int r = 0; r < RPB; ++r) acc[r] = fmaf(h2s[r][q4 * 32 + i], w, acc[r]);
        }
        if (q4 > 0) {
            #pragma unroll
            for (int r = 0; r < RPB; ++r) p3[q4 - 1][r][j] = acc[r];
        }
        __syncthreads();
        if (q4 == 0) {
            const float bb = b3[j];
            #pragma unroll
            for (int r = 0; r < RPB; ++r)
                h3s[r][j] = fmaxf(acc[r] + p3[0][r][j] + p3[1][r][j] + p3[2][r][j] + bb, 0.0f);
        }
    }
    __syncthreads();

    // ---- Output: dot(h3[r], Wo) + bo + dense/FM logit; 32 lanes per row
    {
        const int r = tid >> 5, l = tid & 31;
        float a = h3s[r][l] * Wo[l] + h3s[r][l + 32] * Wo[l + 32];
        a += __shfl_xor(a, 16);
        a += __shfl_xor(a, 8);
        a += __shfl_xor(a, 4);
        a += __shfl_xor(a, 2);
        a += __shfl_xor(a, 1);
        if (l == 0) out[base + r] = a + bo[0] + row_extra[r];
    }
}

extern "C" void kernel_launch(void* const* d_in, const int* in_sizes, int n_in,
                              void* d_out, int out_size, void* d_ws, size_t ws_size,
                              hipStream_t stream) {
    // setup_inputs() dict order:
    const int*   f_user   = (const int*)  d_in[0];
    const int*   f_item   = (const int*)  d_in[1];
    const int*   f_age    = (const int*)  d_in[2];
    const int*   f_gender = (const int*)  d_in[3];
    const int*   f_city   = (const int*)  d_in[4];
    const int*   f_cat    = (const int*)  d_in[5];
    const int*   f_brand  = (const int*)  d_in[6];
    const int*   f_hour   = (const int*)  d_in[7];
    const int*   f_dev    = (const int*)  d_in[8];
    const float* price    = (const float*)d_in[9];
    const float* e_user   = (const float*)d_in[10];
    const float* e_item   = (const float*)d_in[11];
    const float* e_age    = (const float*)d_in[12];
    const float* e_gender = (const float*)d_in[13];
    const float* e_city   = (const float*)d_in[14];
    const float* e_cat    = (const float*)d_in[15];
    const float* e_brand  = (const float*)d_in[16];
    const float* e_hour   = (const float*)d_in[17];
    const float* e_dev    = (const float*)d_in[18];
    const float* w_dense  = (const float*)d_in[19];
    const float* b_dense  = (const float*)d_in[20];
    const float* fm_v     = (const float*)d_in[21];
    const float* W1       = (const float*)d_in[22];
    const float* b1       = (const float*)d_in[23];
    const float* W2       = (const float*)d_in[24];
    const float* b2       = (const float*)d_in[25];
    const float* W3       = (const float*)d_in[26];
    const float* b3       = (const float*)d_in[27];
    const float* Wo       = (const float*)d_in[28];
    const float* bo       = (const float*)d_in[29];
    float* out = (float*)d_out;

    dim3 grid(BATCH / RPB);   // 256 blocks
    dim3 block(256);
    deepfm_fused<<<grid, block, 0, stream>>>(
        f_user, f_item, f_age, f_gender, f_city, f_cat, f_brand, f_hour, f_dev,
        price, e_user, e_item, e_age, e_gender, e_city, e_cat, e_brand, e_hour,
        e_dev, w_dense, b_dense, fm_v, W1, b1, W2, b2, W3, b3, Wo, bo, out);
}

// Round 2
// 132.058 us; speedup vs baseline: 1.3773x; 1.3773x over previous
//
#include <hip/hip_runtime.h>

// DeepFM fused forward, round 2.
// B=2048, RPB=4 rows/block, grid=512 (2 blocks/CU, 8 waves/CU).
// MLP layers: K split across thread-groups (weights read 1x per block),
// float4 LDS activation reads + float4 weight loads, LDS reduction of partials.

#define RPB 4
#define BATCH 2048
#define NF 151193  // sum(VOCABS)+1

// field offsets into the one-hot feature space (cumsum of VOCABS)
#define OFF0 0
#define OFF1 100000
#define OFF2 150000
#define OFF3 150010
#define OFF4 150013
#define OFF5 150113
#define OFF6 150163
#define OFF7 151163
#define OFF8 151187

typedef float f4 __attribute__((ext_vector_type(4)));

__device__ inline f4 relu4(f4 v) {
    f4 r;
    r.x = fmaxf(v.x, 0.0f); r.y = fmaxf(v.y, 0.0f);
    r.z = fmaxf(v.z, 0.0f); r.w = fmaxf(v.w, 0.0f);
    return r;
}

__global__ __launch_bounds__(256, 2) void deepfm_fused(
    const int* __restrict__ f_user, const int* __restrict__ f_item,
    const int* __restrict__ f_age, const int* __restrict__ f_gender,
    const int* __restrict__ f_city, const int* __restrict__ f_cat,
    const int* __restrict__ f_brand, const int* __restrict__ f_hour,
    const int* __restrict__ f_dev, const float* __restrict__ price,
    const float* __restrict__ e_user, const float* __restrict__ e_item,
    const float* __restrict__ e_age, const float* __restrict__ e_gender,
    const float* __restrict__ e_city, const float* __restrict__ e_cat,
    const float* __restrict__ e_brand, const float* __restrict__ e_hour,
    const float* __restrict__ e_dev,
    const float* __restrict__ w_dense, const float* __restrict__ b_dense,
    const float* __restrict__ fm_v,
    const float* __restrict__ W1, const float* __restrict__ b1,
    const float* __restrict__ W2, const float* __restrict__ b2,
    const float* __restrict__ W3, const float* __restrict__ b3,
    const float* __restrict__ Wo, const float* __restrict__ bo,
    float* __restrict__ out)
{
    __shared__ __align__(16) float x[RPB][80];     // deep_in (77, padded to 20 f4)
    __shared__ __align__(16) float h1s[RPB][256];
    __shared__ __align__(16) float h2s[RPB][128];
    __shared__ __align__(16) float h3s[RPB][64];
    __shared__ __align__(16) float pred[4096];     // 16 KB partials, reused per layer
    __shared__ float row_extra[RPB];
    __shared__ float spx[RPB];
    __shared__ int   sid[RPB][9];

    const int tid  = threadIdx.x;
    const int base = blockIdx.x * RPB;

    // ---- Phase A: ids + price
    if (tid < RPB) {
        const int gr = base + tid;
        sid[tid][0] = f_user[gr];
        sid[tid][1] = f_item[gr];
        sid[tid][2] = f_age[gr];
        sid[tid][3] = f_gender[gr];
        sid[tid][4] = f_city[gr];
        sid[tid][5] = f_cat[gr];
        sid[tid][6] = f_brand[gr];
        sid[tid][7] = f_hour[gr];
        sid[tid][8] = f_dev[gr];
        spx[tid]    = price[gr];
    }
    __syncthreads();

    // ---- Phase B: waves 0-1 gather embeddings; wave 2 does FM + dense
    if (tid < 128) {
        const int r = tid >> 5, l = tid & 31;
        if (l < 16) x[r][ 0 + l] = e_user  [sid[r][0] * 16 + l];
        if (l < 16) x[r][16 + l] = e_item  [sid[r][1] * 16 + l];
        if (l <  8) x[r][32 + l] = e_age   [sid[r][2] *  8 + l];
        if (l <  4) x[r][40 + l] = e_gender[sid[r][3] *  4 + l];
        if (l <  8) x[r][44 + l] = e_city  [sid[r][4] *  8 + l];
        if (l <  8) x[r][52 + l] = e_cat   [sid[r][5] *  8 + l];
        if (l <  8) x[r][60 + l] = e_brand [sid[r][6] *  8 + l];
        if (l <  4) x[r][68 + l] = e_hour  [sid[r][7] *  4 + l];
        if (l <  4) x[r][72 + l] = e_dev   [sid[r][8] *  4 + l];
        if (l == 0) x[r][76]     = spx[r];
        if (l == 1) { x[r][77] = 0.0f; }   // pad so f4 chunk 19 is clean
        if (l == 2) { x[r][78] = 0.0f; }
        if (l == 3) { x[r][79] = 0.0f; }
    } else if (tid < 192) {
        const int r = (tid >> 4) & 3, k = tid & 15;
        const float px = spx[r] * (1.0f / 1000.0f);
        float v, s, ssq;
        v = fm_v[(NF - 1) * 16 + k];
        s = px * v; ssq = s * s;
        v = fm_v[(OFF0 + sid[r][0]) * 16 + k]; s += v; ssq += v * v;
        v = fm_v[(OFF1 + sid[r][1]) * 16 + k]; s += v; ssq += v * v;
        v = fm_v[(OFF2 + sid[r][2]) * 16 + k]; s += v; ssq += v * v;
        v = fm_v[(OFF3 + sid[r][3]) * 16 + k]; s += v; ssq += v * v;
        v = fm_v[(OFF4 + sid[r][4]) * 16 + k]; s += v; ssq += v * v;
        v = fm_v[(OFF5 + sid[r][5]) * 16 + k]; s += v; ssq += v * v;
        v = fm_v[(OFF6 + sid[r][6]) * 16 + k]; s += v; ssq += v * v;
        v = fm_v[(OFF7 + sid[r][7]) * 16 + k]; s += v; ssq += v * v;
        v = fm_v[(OFF8 + sid[r][8]) * 16 + k]; s += v; ssq += v * v;
        float q = 0.5f * (s * s - ssq);
        if (k == 0) {
            float d = b_dense[0] + px * w_dense[NF - 1];
            d += w_dense[OFF0 + sid[r][0]];
            d += w_dense[OFF1 + sid[r][1]];
            d += w_dense[OFF2 + sid[r][2]];
            d += w_dense[OFF3 + sid[r][3]];
            d += w_dense[OFF4 + sid[r][4]];
            d += w_dense[OFF5 + sid[r][5]];
            d += w_dense[OFF6 + sid[r][6]];
            d += w_dense[OFF7 + sid[r][7]];
            d += w_dense[OFF8 + sid[r][8]];
            q += d;
        }
        q += __shfl_xor(q, 8);
        q += __shfl_xor(q, 4);
        q += __shfl_xor(q, 2);
        q += __shfl_xor(q, 1);
        if (k == 0) row_extra[r] = q;
    }
    __syncthreads();

    // ---- Layer 1: (4 x 77) @ (77 x 256). 64 col-threads (4 cols) x 4 K-groups.
    {
        const int kg = tid >> 6, ct = tid & 63;
        const f4* W1v = (const f4*)W1;        // row i = 64 f4
        const f4* xv  = (const f4*)x;         // row r = 20 f4
        f4 acc0 = 0, acc1 = 0, acc2 = 0, acc3 = 0;
        const int i0 = 20 * kg;
        const int nch = (kg == 3) ? 4 : 5;
        for (int c = 0; c < nch; ++c) {
            const int i = i0 + 4 * c, q = i >> 2;
            f4 xa0 = xv[ 0 + q];
            f4 xa1 = xv[20 + q];
            f4 xa2 = xv[40 + q];
            f4 xa3 = xv[60 + q];
            f4 w0 = W1v[(i + 0) * 64 + ct];
            f4 w1 = W1v[(i + 1) * 64 + ct];
            f4 w2 = W1v[(i + 2) * 64 + ct];
            f4 w3 = W1v[(i + 3) * 64 + ct];
            acc0 += xa0.x * w0 + xa0.y * w1 + xa0.z * w2 + xa0.w * w3;
            acc1 += xa1.x * w0 + xa1.y * w1 + xa1.z * w2 + xa1.w * w3;
            acc2 += xa2.x * w0 + xa2.y * w1 + xa2.z * w2 + xa2.w * w3;
            acc3 += xa3.x * w0 + xa3.y * w1 + xa3.z * w2 + xa3.w * w3;
        }
        if (kg == 3) {   // tail i = 76
            f4 w = W1v[76 * 64 + ct];
            acc0 += x[0][76] * w;
            acc1 += x[1][76] * w;
            acc2 += x[2][76] * w;
            acc3 += x[3][76] * w;
        }
        f4* pv = (f4*)pred;                   // p1[kg][r][256] as f4: (kg*4+r)*64+ct
        pv[(kg * 4 + 0) * 64 + ct] = acc0;
        pv[(kg * 4 + 1) * 64 + ct] = acc1;
        pv[(kg * 4 + 2) * 64 + ct] = acc2;
        pv[(kg * 4 + 3) * 64 + ct] = acc3;
    }
    __syncthreads();
    {   // reduce 4 partials + bias + relu -> h1s
        const int r = tid >> 6, c4 = tid & 63;
        const f4* pv = (const f4*)pred;
        f4 s = pv[(0 + r) * 64 + c4] + pv[(4 + r) * 64 + c4]
             + pv[(8 + r) * 64 + c4] + pv[(12 + r) * 64 + c4];
        s += ((const f4*)b1)[c4];
        ((f4*)h1s)[r * 64 + c4] = relu4(s);
    }
    __syncthreads();

    // ---- Layer 2: (4 x 256) @ (256 x 128). 32 col-threads (4 cols) x 8 K-groups (32 K).
    {
        const int kg = tid >> 5, ct = tid & 31;
        const f4* W2v = (const f4*)W2;        // row i = 32 f4
        const f4* hv  = (const f4*)h1s;       // row r = 64 f4
        f4 acc0 = 0, acc1 = 0, acc2 = 0, acc3 = 0;
        const int i0 = 32 * kg;
        #pragma unroll
        for (int c = 0; c < 8; ++c) {
            const int i = i0 + 4 * c, q = i >> 2;
            f4 xa0 = hv[  0 + q];
            f4 xa1 = hv[ 64 + q];
            f4 xa2 = hv[128 + q];
            f4 xa3 = hv[192 + q];
            f4 w0 = W2v[(i + 0) * 32 + ct];
            f4 w1 = W2v[(i + 1) * 32 + ct];
            f4 w2 = W2v[(i + 2) * 32 + ct];
            f4 w3 = W2v[(i + 3) * 32 + ct];
            acc0 += xa0.x * w0 + xa0.y * w1 + xa0.z * w2 + xa0.w * w3;
            acc1 += xa1.x * w0 + xa1.y * w1 + xa1.z * w2 + xa1.w * w3;
            acc2 += xa2.x * w0 + xa2.y * w1 + xa2.z * w2 + xa2.w * w3;
            acc3 += xa3.x * w0 + xa3.y * w1 + xa3.z * w2 + xa3.w * w3;
        }
        f4* pv = (f4*)pred;                   // p2[kg][r][128] as f4: (kg*4+r)*32+ct
        pv[(kg * 4 + 0) * 32 + ct] = acc0;
        pv[(kg * 4 + 1) * 32 + ct] = acc1;
        pv[(kg * 4 + 2) * 32 + ct] = acc2;
        pv[(kg * 4 + 3) * 32 + ct] = acc3;
    }
    __syncthreads();
    if (tid < 128) {   // reduce 8 partials + bias + relu -> h2s
        const int r = tid >> 5, c4 = tid & 31;
        const f4* pv = (const f4*)pred;
        f4 s = 0;
        #pragma unroll
        for (int kg = 0; kg < 8; ++kg) s += pv[(kg * 4 + r) * 32 + c4];
        s += ((const f4*)b2)[c4];
        ((f4*)h2s)[r * 32 + c4] = relu4(s);
    }
    __syncthreads();

    // ---- Layer 3: (4 x 128) @ (128 x 64). 16 col-threads (4 cols) x 16 K-groups (8 K).
    {
        const int kg = tid >> 4, ct = tid & 15;
        const f4* W3v = (const f4*)W3;        // row i = 16 f4
        const f4* hv  = (const f4*)h2s;       // row r = 32 f4
        f4 acc0 = 0, acc1 = 0, acc2 = 0, acc3 = 0;
        const int i0 = 8 * kg;
        #pragma unroll
        for (int c = 0; c < 2; ++c) {
            const int i = i0 + 4 * c, q = i >> 2;
            f4 xa0 = hv[ 0 + q];
            f4 xa1 = hv[32 + q];
            f4 xa2 = hv[64 + q];
            f4 xa3 = hv[96 + q];
            f4 w0 = W3v[(i + 0) * 16 + ct];
            f4 w1 = W3v[(i + 1) * 16 + ct];
            f4 w2 = W3v[(i + 2) * 16 + ct];
            f4 w3 = W3v[(i + 3) * 16 + ct];
            acc0 += xa0.x * w0 + xa0.y * w1 + xa0.z * w2 + xa0.w * w3;
            acc1 += xa1.x * w0 + xa1.y * w1 + xa1.z * w2 + xa1.w * w3;
            acc2 += xa2.x * w0 + xa2.y * w1 + xa2.z * w2 + xa2.w * w3;
            acc3 += xa3.x * w0 + xa3.y * w1 + xa3.z * w2 + xa3.w * w3;
        }
        f4* pv = (f4*)pred;                   // p3[kg][r][64] as f4: (kg*4+r)*16+ct
        pv[(kg * 4 + 0) * 16 + ct] = acc0;
        pv[(kg * 4 + 1) * 16 + ct] = acc1;
        pv[(kg * 4 + 2) * 16 + ct] = acc2;
        pv[(kg * 4 + 3) * 16 + ct] = acc3;
    }
    __syncthreads();
    if (tid < 64) {    // reduce 16 partials + bias + relu -> h3s
        const int r = tid >> 4, c4 = tid & 15;
        const f4* pv = (const f4*)pred;
        f4 s = 0;
        #pragma unroll
        for (int kg = 0; kg < 16; ++kg) s += pv[(kg * 4 + r) * 16 + c4];
        s += ((const f4*)b3)[c4];
        ((f4*)h3s)[r * 16 + c4] = relu4(s);
    }
    __syncthreads();

    // ---- Output: dot(h3[r], Wo) + bo + dense/FM; 32 lanes per row, 4 rows
    if (tid < 128) {
        const int r = tid >> 5, l = tid & 31;
        float a = h3s[r][l] * Wo[l] + h3s[r][l + 32] * Wo[l + 32];
        a += __shfl_xor(a, 16);
        a += __shfl_xor(a, 8);
        a += __shfl_xor(a, 4);
        a += __shfl_xor(a, 2);
        a += __shfl_xor(a, 1);
        if (l == 0) out[base + r] = a + bo[0] + row_extra[r];
    }
}

extern "C" void kernel_launch(void* const* d_in, const int* in_sizes, int n_in,
                              void* d_out, int out_size, void* d_ws, size_t ws_size,
                              hipStream_t stream) {
    const int*   f_user   = (const int*)  d_in[0];
    const int*   f_item   = (const int*)  d_in[1];
    const int*   f_age    = (const int*)  d_in[2];
    const int*   f_gender = (const int*)  d_in[3];
    const int*   f_city   = (const int*)  d_in[4];
    const int*   f_cat    = (const int*)  d_in[5];
    const int*   f_brand  = (const int*)  d_in[6];
    const int*   f_hour   = (const int*)  d_in[7];
    const int*   f_dev    = (const int*)  d_in[8];
    const float* price    = (const float*)d_in[9];
    const float* e_user   = (const float*)d_in[10];
    const float* e_item   = (const float*)d_in[11];
    const float* e_age    = (const float*)d_in[12];
    const float* e_gender = (const float*)d_in[13];
    const float* e_city   = (const float*)d_in[14];
    const float* e_cat    = (const float*)d_in[15];
    const float* e_brand  = (const float*)d_in[16];
    const float* e_hour   = (const float*)d_in[17];
    const float* e_dev    = (const float*)d_in[18];
    const float* w_dense  = (const float*)d_in[19];
    const float* b_dense  = (const float*)d_in[20];
    const float* fm_v     = (const float*)d_in[21];
    const float* W1       = (const float*)d_in[22];
    const float* b1       = (const float*)d_in[23];
    const float* W2       = (const float*)d_in[24];
    const float* b2       = (const float*)d_in[25];
    const float* W3       = (const float*)d_in[26];
    const float* b3       = (const float*)d_in[27];
    const float* Wo       = (const float*)d_in[28];
    const float* bo       = (const float*)d_in[29];
    float* out = (float*)d_out;

    dim3 grid(BATCH / RPB);   // 512 blocks -> 2 blocks/CU
    dim3 block(256);
    deepfm_fused<<<grid, block, 0, stream>>>(
        f_user, f_item, f_age, f_gender, f_city, f_cat, f_brand, f_hour, f_dev,
        price, e_user, e_item, e_age, e_gender, e_city, e_cat, e_brand, e_hour,
        e_dev, w_dense, b_dense, fm_v, W1, b1, W2, b2, W3, b3, Wo, bo, out);
}